// Round 5
// baseline (3649.575 us; speedup 1.0000x reference)
//
#include <hip/hip_runtime.h>

// GCN 2-layer forward: out = GCNConv(relu(GCNConv(x,W1,b1)),W2,b2), returns (out, x_emb)
// N=100000 nodes, E=6400000 edges, feature dims 16 -> 8 -> 2.
//
// Self-loops are never materialized: node i's self contribution is dinv[i]^2 * h[i],
// added analytically in the epilogue kernels (deg includes the +1 loop weight).
//
//   k_detect : 1 thread — sniff whether edge_index arrived as int32 or int64
//              (values < 1e5, so int64 => odd 4B words all zero; P[false pos] ~ 1e-160)
//   k_prep   : atomic deg[col] += w                       (reads col-half of ei only)
//   k_node1  : dinv = rsqrt(deg+1);  h1 = x @ W1          (per-node)
//   k_agg1   : agg1[col] += dinv[r]*w*dinv[c] * h1[row]   (8 f32 atomics/edge, L2-resident)
//   k_epi1   : x_emb = agg1 + dinv^2*h1 + b1; h2 = relu(x_emb)@W2
//   k_agg2   : agg2[col] += norm * h2[row]                (2 atomics/edge)
//   k_epi2   : out = agg2 + dinv^2*h2 + b2
//
// Edge kernels stream edge_index/edge_weight with 16B vector loads, 4 edges/thread
// (G13: hipcc won't auto-vectorize; 16B/lane is the coalescing sweet spot).
// NE % 4 == 0 so there is no scalar tail.
//
// All f32 accumulations use unsafeAtomicAdd: plain atomicAdd(float*) may lower to a
// CAS loop (IEEE denorm preservation) depending on arch/flags; under our mean 64-way
// address contention a CAS loop would retry-storm. unsafeAtomicAdd always emits the
// native global_atomic_add_f32 (device scope; denorm-flush is irrelevant at our
// absmax threshold with unit-scale data).

#define NN 100000
#define NE 6400000

__device__ __forceinline__ void atomAdd(float* p, float v) {
#if defined(__HIP_DEVICE_COMPILE__)
    unsafeAtomicAdd(p, v);
#else
    atomicAdd(p, v);
#endif
}

__global__ void k_detect(const int* __restrict__ ei32, int* __restrict__ flag) {
    int z = 0;
#pragma unroll
    for (int i = 1; i < 64; i += 2) z |= ei32[i];  // high words if int64
    *flag = (z == 0) ? 1 : 0;
}

__global__ __launch_bounds__(256) void k_prep(const void* __restrict__ ei,
                                              const float* __restrict__ ew,
                                              const int* __restrict__ flag,
                                              float* __restrict__ deg) {
    const int is64 = *flag;
    const int stride = gridDim.x * blockDim.x;
    const int nv = NE / 4;
    const float4* ewv = (const float4*)ew;
    if (is64) {
        const longlong2* c2 = (const longlong2*)((const long long*)ei + NE);
        for (int v = blockIdx.x * blockDim.x + threadIdx.x; v < nv; v += stride) {
            longlong2 ca = c2[2 * v], cb = c2[2 * v + 1];
            float4 w = ewv[v];
            atomAdd(&deg[(int)ca.x], w.x);
            atomAdd(&deg[(int)ca.y], w.y);
            atomAdd(&deg[(int)cb.x], w.z);
            atomAdd(&deg[(int)cb.y], w.w);
        }
    } else {
        const int4* c4 = (const int4*)((const int*)ei + NE);
        for (int v = blockIdx.x * blockDim.x + threadIdx.x; v < nv; v += stride) {
            int4 c = c4[v];
            float4 w = ewv[v];
            atomAdd(&deg[c.x], w.x);
            atomAdd(&deg[c.y], w.y);
            atomAdd(&deg[c.z], w.z);
            atomAdd(&deg[c.w], w.w);
        }
    }
}

__global__ __launch_bounds__(256) void k_node1(const float* __restrict__ x,
                                               const float* __restrict__ W1,
                                               const float* __restrict__ deg,
                                               float* __restrict__ dinv,
                                               float* __restrict__ h1) {
    __shared__ float sW[128];  // W1 is 16x8
    if (threadIdx.x < 128) sW[threadIdx.x] = W1[threadIdx.x];
    __syncthreads();
    int i = blockIdx.x * blockDim.x + threadIdx.x;
    if (i >= NN) return;
    float d = deg[i] + 1.0f;           // self-loop adds weight 1
    dinv[i] = rsqrtf(d);               // d >= 1 always, no zero guard needed
    const float4* xp = reinterpret_cast<const float4*>(x + (size_t)i * 16);
    float acc[8];
#pragma unroll
    for (int j = 0; j < 8; ++j) acc[j] = 0.0f;
#pragma unroll
    for (int kq = 0; kq < 4; ++kq) {
        float4 v = xp[kq];
        float vv[4] = {v.x, v.y, v.z, v.w};
#pragma unroll
        for (int kk = 0; kk < 4; ++kk) {
            int k = kq * 4 + kk;
#pragma unroll
            for (int j = 0; j < 8; ++j) acc[j] += vv[kk] * sW[k * 8 + j];
        }
    }
    float4* hp = reinterpret_cast<float4*>(h1 + (size_t)i * 8);
    hp[0] = make_float4(acc[0], acc[1], acc[2], acc[3]);
    hp[1] = make_float4(acc[4], acc[5], acc[6], acc[7]);
}

__device__ __forceinline__ void agg1_edge(int r, int c, float w,
                                          const float* __restrict__ dinv,
                                          const float* __restrict__ h1,
                                          float* __restrict__ agg1) {
    float nrm = dinv[r] * w * dinv[c];
    const float4* hp = reinterpret_cast<const float4*>(h1 + (size_t)r * 8);
    float4 a = hp[0];
    float4 b = hp[1];
    float* o = agg1 + (size_t)c * 8;
    atomAdd(o + 0, nrm * a.x);
    atomAdd(o + 1, nrm * a.y);
    atomAdd(o + 2, nrm * a.z);
    atomAdd(o + 3, nrm * a.w);
    atomAdd(o + 4, nrm * b.x);
    atomAdd(o + 5, nrm * b.y);
    atomAdd(o + 6, nrm * b.z);
    atomAdd(o + 7, nrm * b.w);
}

__global__ __launch_bounds__(256) void k_agg1(const void* __restrict__ ei,
                                              const float* __restrict__ ew,
                                              const int* __restrict__ flag,
                                              const float* __restrict__ dinv,
                                              const float* __restrict__ h1,
                                              float* __restrict__ agg1) {
    const int is64 = *flag;
    const int stride = gridDim.x * blockDim.x;
    const int nv = NE / 4;
    const float4* ewv = (const float4*)ew;
    if (is64) {
        const longlong2* r2 = (const longlong2*)ei;
        const longlong2* c2 = (const longlong2*)((const long long*)ei + NE);
        for (int v = blockIdx.x * blockDim.x + threadIdx.x; v < nv; v += stride) {
            longlong2 ra = r2[2 * v], rb = r2[2 * v + 1];
            longlong2 ca = c2[2 * v], cb = c2[2 * v + 1];
            float4 w = ewv[v];
            agg1_edge((int)ra.x, (int)ca.x, w.x, dinv, h1, agg1);
            agg1_edge((int)ra.y, (int)ca.y, w.y, dinv, h1, agg1);
            agg1_edge((int)rb.x, (int)cb.x, w.z, dinv, h1, agg1);
            agg1_edge((int)rb.y, (int)cb.y, w.w, dinv, h1, agg1);
        }
    } else {
        const int4* r4 = (const int4*)ei;
        const int4* c4 = (const int4*)((const int*)ei + NE);
        for (int v = blockIdx.x * blockDim.x + threadIdx.x; v < nv; v += stride) {
            int4 r = r4[v];
            int4 c = c4[v];
            float4 w = ewv[v];
            agg1_edge(r.x, c.x, w.x, dinv, h1, agg1);
            agg1_edge(r.y, c.y, w.y, dinv, h1, agg1);
            agg1_edge(r.z, c.z, w.z, dinv, h1, agg1);
            agg1_edge(r.w, c.w, w.w, dinv, h1, agg1);
        }
    }
}

__global__ __launch_bounds__(256) void k_epi1(const float* __restrict__ agg1,
                                              const float* __restrict__ h1,
                                              const float* __restrict__ dinv,
                                              const float* __restrict__ W2,  // 8x2
                                              const float* __restrict__ b1,
                                              float* __restrict__ xemb,
                                              float* __restrict__ h2) {
    int i = blockIdx.x * blockDim.x + threadIdx.x;
    if (i >= NN) return;
    float di = dinv[i];
    float d2 = di * di;
    const float4* ap = reinterpret_cast<const float4*>(agg1 + (size_t)i * 8);
    const float4* hp = reinterpret_cast<const float4*>(h1 + (size_t)i * 8);
    float4 a0 = ap[0], a1 = ap[1];
    float4 g0 = hp[0], g1 = hp[1];
    float e[8];
    e[0] = a0.x + d2 * g0.x + b1[0];
    e[1] = a0.y + d2 * g0.y + b1[1];
    e[2] = a0.z + d2 * g0.z + b1[2];
    e[3] = a0.w + d2 * g0.w + b1[3];
    e[4] = a1.x + d2 * g1.x + b1[4];
    e[5] = a1.y + d2 * g1.y + b1[5];
    e[6] = a1.z + d2 * g1.z + b1[6];
    e[7] = a1.w + d2 * g1.w + b1[7];
    float4* xo = reinterpret_cast<float4*>(xemb + (size_t)i * 8);
    xo[0] = make_float4(e[0], e[1], e[2], e[3]);
    xo[1] = make_float4(e[4], e[5], e[6], e[7]);
    float s0 = 0.0f, s1 = 0.0f;
#pragma unroll
    for (int j = 0; j < 8; ++j) {
        float r = fmaxf(e[j], 0.0f);
        s0 += r * W2[j * 2 + 0];
        s1 += r * W2[j * 2 + 1];
    }
    float2* ho = reinterpret_cast<float2*>(h2 + (size_t)i * 2);
    *ho = make_float2(s0, s1);
}

__device__ __forceinline__ void agg2_edge(int r, int c, float w,
                                          const float* __restrict__ dinv,
                                          const float* __restrict__ h2,
                                          float* __restrict__ agg2) {
    float nrm = dinv[r] * w * dinv[c];
    const float2* hp = reinterpret_cast<const float2*>(h2 + (size_t)r * 2);
    float2 v = *hp;
    float* o = agg2 + (size_t)c * 2;
    atomAdd(o + 0, nrm * v.x);
    atomAdd(o + 1, nrm * v.y);
}

__global__ __launch_bounds__(256) void k_agg2(const void* __restrict__ ei,
                                              const float* __restrict__ ew,
                                              const int* __restrict__ flag,
                                              const float* __restrict__ dinv,
                                              const float* __restrict__ h2,
                                              float* __restrict__ agg2) {
    const int is64 = *flag;
    const int stride = gridDim.x * blockDim.x;
    const int nv = NE / 4;
    const float4* ewv = (const float4*)ew;
    if (is64) {
        const longlong2* r2 = (const longlong2*)ei;
        const longlong2* c2 = (const longlong2*)((const long long*)ei + NE);
        for (int v = blockIdx.x * blockDim.x + threadIdx.x; v < nv; v += stride) {
            longlong2 ra = r2[2 * v], rb = r2[2 * v + 1];
            longlong2 ca = c2[2 * v], cb = c2[2 * v + 1];
            float4 w = ewv[v];
            agg2_edge((int)ra.x, (int)ca.x, w.x, dinv, h2, agg2);
            agg2_edge((int)ra.y, (int)ca.y, w.y, dinv, h2, agg2);
            agg2_edge((int)rb.x, (int)cb.x, w.z, dinv, h2, agg2);
            agg2_edge((int)rb.y, (int)cb.y, w.w, dinv, h2, agg2);
        }
    } else {
        const int4* r4 = (const int4*)ei;
        const int4* c4 = (const int4*)((const int*)ei + NE);
        for (int v = blockIdx.x * blockDim.x + threadIdx.x; v < nv; v += stride) {
            int4 r = r4[v];
            int4 c = c4[v];
            float4 w = ewv[v];
            agg2_edge(r.x, c.x, w.x, dinv, h2, agg2);
            agg2_edge(r.y, c.y, w.y, dinv, h2, agg2);
            agg2_edge(r.z, c.z, w.z, dinv, h2, agg2);
            agg2_edge(r.w, c.w, w.w, dinv, h2, agg2);
        }
    }
}

__global__ __launch_bounds__(256) void k_epi2(const float* __restrict__ agg2,
                                              const float* __restrict__ h2,
                                              const float* __restrict__ dinv,
                                              const float* __restrict__ b2,
                                              float* __restrict__ out) {
    int i = blockIdx.x * blockDim.x + threadIdx.x;
    if (i >= NN) return;
    float di = dinv[i];
    float d2 = di * di;
    const float2* ap = reinterpret_cast<const float2*>(agg2 + (size_t)i * 2);
    const float2* hp = reinterpret_cast<const float2*>(h2 + (size_t)i * 2);
    float2 a = *ap, h = *hp;
    float2* oo = reinterpret_cast<float2*>(out + (size_t)i * 2);
    *oo = make_float2(a.x + d2 * h.x + b2[0], a.y + d2 * h.y + b2[1]);
}

extern "C" void kernel_launch(void* const* d_in, const int* in_sizes, int n_in,
                              void* d_out, int out_size, void* d_ws, size_t ws_size,
                              hipStream_t stream) {
    const float* x  = (const float*)d_in[0];
    const void*  ei = d_in[1];                 // int32 or int64 — detected on device
    const float* ew = (const float*)d_in[2];
    const float* W1 = (const float*)d_in[3];
    const float* b1 = (const float*)d_in[4];
    const float* W2 = (const float*)d_in[5];
    const float* b2 = (const float*)d_in[6];

    float* out  = (float*)d_out;               // [NN*2] (layer-2 out) ...
    float* xemb = out + (size_t)NN * 2;        // ... then [NN*8] x_emb

    // workspace layout (deg,agg1,agg2 contiguous -> one zeroing memset; ~8.8 MB total)
    float* deg  = (float*)d_ws;                // NN
    float* agg1 = deg + NN;                    // NN*8
    float* agg2 = agg1 + (size_t)NN * 8;       // NN*2
    float* dinv = agg2 + (size_t)NN * 2;       // NN
    float* h1   = dinv + NN;                   // NN*8
    float* h2   = h1 + (size_t)NN * 8;         // NN*2
    int*   flag = (int*)(h2 + (size_t)NN * 2); // 1

    // harness poisons ws with 0xAA before every timed launch — zero the accumulators
    hipMemsetAsync(deg, 0, (size_t)NN * (1 + 8 + 2) * sizeof(float), stream);

    const int EB = 2048;              // edge kernels: grid-stride, 4 edges/thread
    const int NB = (NN + 255) / 256;  // node kernels: 1 thread per node

    k_detect<<<1, 1, 0, stream>>>((const int*)ei, flag);
    k_prep <<<EB, 256, 0, stream>>>(ei, ew, flag, deg);
    k_node1<<<NB, 256, 0, stream>>>(x, W1, deg, dinv, h1);
    k_agg1 <<<EB, 256, 0, stream>>>(ei, ew, flag, dinv, h1, agg1);
    k_epi1 <<<NB, 256, 0, stream>>>(agg1, h1, dinv, W2, b1, xemb, h2);
    k_agg2 <<<EB, 256, 0, stream>>>(ei, ew, flag, dinv, h2, agg2);
    k_epi2 <<<NB, 256, 0, stream>>>(agg2, h2, dinv, b2, out);
}

// Round 8
// 568.093 us; speedup vs baseline: 6.4243x; 6.4243x over previous
//
#include <hip/hip_runtime.h>

// GCN 2-layer forward: out = GCNConv(relu(GCNConv(x,W1,b1)),W2,b2), returns (out, x_emb)
// N=100000 nodes, E=6400000 edges, feature dims 16 -> 8 -> 2.
//
// ROUND-5 PROFILE LAW: device-scope f32 atomics flush through L2 at 32B each;
// kernel time ~= device_atomic_count / 20G-per-s (k_agg1: 51.2M atomics = 2587us,
// 8.3% HBM, VALUBusy 0.13%). Round-5 FETCH (83MB) also proved edge_index is int32.
// => minimize DEVICE atomics structurally:
//
//  FAST PATH (ws >= ~87MB):
//   k_detect : sniff int32 vs int64 edge_index (1 thread; insurance)
//   k_bucket : partition edges into 50 col-groups of 2000 nodes; 8B records
//              (r:17b | c_local:11b | w:f32). Device atomics: 50 * 3125 blocks = 156K.
//   k_deg    : per (group,chunk): LDS accumulate deg, write partial (no dev atomics)
//   k_node1m : deg = 1 + sum partials; dinv = rsqrt; h1s = dinv * (x@W1)
//   k_gather1: per (group,chunk): LDS acc[2000][8] += w*h1s[r]  (dinv[r] pre-folded:
//              one fewer random gather per record); write partial
//   k_epi1m  : xemb = di*(sum + h1s) + b1  (self-loop d^2*h == di*h1s, exact);
//              h2s = di * (relu(xemb)@W2)
//   k_gather2/k_epi2m : same for layer 2 (2 features)
//  Gather/deg kernels run 512 threads (64KB LDS caps 2 blocks/CU; 512t doubles
//  resident waves for L2-gather latency hiding). KCH: 10 (~104MB ws) else 6 (~87MB).
//
//  FALLBACK (ws too small): round-5 passing kernels (atomic scatter), unchanged.

#define NN 100000
#define NE 6400000

#define GROUPS 50
#define GSIZE  2000      // NN / GROUPS
#define CAP    140000    // per-group capacity (mean 128000, sigma~354 -> +34 sigma)
#define BK     2048      // edges per bucket block
#define NBB    (NE/BK)   // 3125 exactly

// ---------- shared helpers ----------

__device__ __forceinline__ void atomAdd(float* p, float v) {
#if defined(__HIP_DEVICE_COMPILE__)
    unsafeAtomicAdd(p, v);   // native global_atomic_add_f32 (fallback path only)
#else
    atomicAdd(p, v);
#endif
}

__device__ __forceinline__ void load4(const void* __restrict__ ei, int is64, size_t q,
                                      size_t halfoff, int v[4]) {
    if (is64) {
        const longlong2* p = (const longlong2*)((const long long*)ei + halfoff);
        longlong2 a = p[2 * q], b = p[2 * q + 1];
        v[0] = (int)a.x; v[1] = (int)a.y; v[2] = (int)b.x; v[3] = (int)b.y;
    } else {
        int4 t = ((const int4*)((const int*)ei + halfoff))[q];
        v[0] = t.x; v[1] = t.y; v[2] = t.z; v[3] = t.w;
    }
}

__global__ void k_detect(const int* __restrict__ ei32, int* __restrict__ flag) {
    int z = 0;
#pragma unroll
    for (int i = 1; i < 64; i += 2) z |= ei32[i];  // high words if int64
    *flag = (z == 0) ? 1 : 0;
}

// ---------- FAST PATH ----------

__global__ __launch_bounds__(256) void k_bucket(const void* __restrict__ ei,
                                                const float* __restrict__ ew,
                                                const int* __restrict__ flag,
                                                unsigned* __restrict__ cursors,
                                                unsigned long long* __restrict__ buckets) {
    __shared__ int hist[GROUPS];
    __shared__ int base[GROUPS];
    const int is64 = *flag;
    const int t = threadIdx.x;
    if (t < GROUPS) hist[t] = 0;
    __syncthreads();
    const size_t q0 = (size_t)blockIdx.x * (BK / 4);
    // pass 1: count cols per group (chunk stays cache-hot for pass 2)
#pragma unroll
    for (int it = 0; it < BK / 4 / 256; ++it) {  // 2 iters
        size_t q = q0 + (size_t)it * 256 + t;
        int c[4]; load4(ei, is64, q, NE, c);
#pragma unroll
        for (int k = 0; k < 4; ++k) atomicAdd(&hist[c[k] / GSIZE], 1);
    }
    __syncthreads();
    if (t < GROUPS) {
        base[t] = (int)atomicAdd(&cursors[t], (unsigned)hist[t]);  // 50 device atomics/block
        hist[t] = 0;                                               // reuse as intra-block cursor
    }
    __syncthreads();
    // pass 2: place records (per-group streams are contiguous within a block)
#pragma unroll
    for (int it = 0; it < BK / 4 / 256; ++it) {
        size_t q = q0 + (size_t)it * 256 + t;
        int r[4], c[4];
        load4(ei, is64, q, 0, r);
        load4(ei, is64, q, NE, c);
        float4 wv = ((const float4*)ew)[q];
        float w[4] = {wv.x, wv.y, wv.z, wv.w};
#pragma unroll
        for (int k = 0; k < 4; ++k) {
            int g = c[k] / GSIZE;
            int cl = c[k] - g * GSIZE;
            int idx = atomicAdd(&hist[g], 1) + base[g];  // LDS atomic
            if (idx < CAP) {
                unsigned pk = (unsigned)r[k] | ((unsigned)cl << 17);
                buckets[(size_t)g * CAP + idx] =
                    (unsigned long long)pk | ((unsigned long long)__float_as_uint(w[k]) << 32);
            }
        }
    }
}

__global__ __launch_bounds__(512) void k_deg(const unsigned* __restrict__ cursors,
                                             const unsigned long long* __restrict__ buckets,
                                             int kch,
                                             float* __restrict__ degpart) {
    __shared__ float acc[GSIZE];
    const int t = threadIdx.x;
    const int g = blockIdx.x / kch, j = blockIdx.x % kch;
    for (int i = t; i < GSIZE; i += 512) acc[i] = 0.0f;
    __syncthreads();
    unsigned cu = cursors[g];
    const int cnt = (int)(cu < (unsigned)CAP ? cu : (unsigned)CAP);
    const int cpk = (cnt + kch - 1) / kch;
    const int lo = j * cpk;
    const int hi = (lo + cpk < cnt) ? lo + cpk : cnt;
    const unsigned long long* B = buckets + (size_t)g * CAP;
    for (int i = lo + t; i < hi; i += 512) {
        unsigned long long rec = B[i];
        int cl = ((unsigned)rec) >> 17;
        float w = __uint_as_float((unsigned)(rec >> 32));
        atomicAdd(&acc[cl], w);  // LDS atomic
    }
    __syncthreads();
    float* dst = degpart + ((size_t)g * kch + j) * GSIZE;
    for (int i = t; i < GSIZE; i += 512) dst[i] = acc[i];
}

template <int KCH>
__global__ __launch_bounds__(256) void k_node1m(const float* __restrict__ x,
                                                const float* __restrict__ W1,
                                                const float* __restrict__ degpart,
                                                float* __restrict__ dinv,
                                                float* __restrict__ h1s) {
    __shared__ float sW[128];  // W1 is 16x8
    if (threadIdx.x < 128) sW[threadIdx.x] = W1[threadIdx.x];
    __syncthreads();
    int i = blockIdx.x * blockDim.x + threadIdx.x;
    if (i >= NN) return;
    int g = i / GSIZE, il = i - g * GSIZE;
    float d = 1.0f;  // self-loop weight
#pragma unroll
    for (int j = 0; j < KCH; ++j) d += degpart[((size_t)g * KCH + j) * GSIZE + il];
    float di = rsqrtf(d);
    dinv[i] = di;
    const float4* xp = reinterpret_cast<const float4*>(x + (size_t)i * 16);
    float acc[8];
#pragma unroll
    for (int j = 0; j < 8; ++j) acc[j] = 0.0f;
#pragma unroll
    for (int kq = 0; kq < 4; ++kq) {
        float4 v = xp[kq];
        float vv[4] = {v.x, v.y, v.z, v.w};
#pragma unroll
        for (int kk = 0; kk < 4; ++kk) {
            int k = kq * 4 + kk;
#pragma unroll
            for (int j = 0; j < 8; ++j) acc[j] += vv[kk] * sW[k * 8 + j];
        }
    }
    // store dinv-prescaled features: gather then needs NO dinv[r] lookup
    float4* hp = reinterpret_cast<float4*>(h1s + (size_t)i * 8);
    hp[0] = make_float4(di * acc[0], di * acc[1], di * acc[2], di * acc[3]);
    hp[1] = make_float4(di * acc[4], di * acc[5], di * acc[6], di * acc[7]);
}

__global__ __launch_bounds__(512) void k_gather1(const unsigned* __restrict__ cursors,
                                                 const unsigned long long* __restrict__ buckets,
                                                 int kch,
                                                 const float* __restrict__ h1s,
                                                 float* __restrict__ g1part) {
    __shared__ float acc[GSIZE * 8];  // 64000 B -> 2 blocks/CU; 512t = latency hiding
    const int t = threadIdx.x;
    const int g = blockIdx.x / kch, j = blockIdx.x % kch;
    for (int i = t; i < GSIZE * 8; i += 512) acc[i] = 0.0f;
    __syncthreads();
    unsigned cu = cursors[g];
    const int cnt = (int)(cu < (unsigned)CAP ? cu : (unsigned)CAP);
    const int cpk = (cnt + kch - 1) / kch;
    const int lo = j * cpk;
    const int hi = (lo + cpk < cnt) ? lo + cpk : cnt;
    const unsigned long long* B = buckets + (size_t)g * CAP;
    for (int i = lo + t; i < hi; i += 512) {
        unsigned long long rec = B[i];
        unsigned pk = (unsigned)rec;
        int r = pk & 0x1FFFF;
        int cl = pk >> 17;
        float w = __uint_as_float((unsigned)(rec >> 32));  // nrm = w * dinv[r] pre-folded in h1s
        const float4* hp = (const float4*)(h1s + (size_t)r * 8);
        float4 a = hp[0], b = hp[1];
        float* A = acc + cl * 8;
        atomicAdd(A + 0, w * a.x);
        atomicAdd(A + 1, w * a.y);
        atomicAdd(A + 2, w * a.z);
        atomicAdd(A + 3, w * a.w);
        atomicAdd(A + 4, w * b.x);
        atomicAdd(A + 5, w * b.y);
        atomicAdd(A + 6, w * b.z);
        atomicAdd(A + 7, w * b.w);
    }
    __syncthreads();
    float* dst = g1part + ((size_t)g * kch + j) * (GSIZE * 8);
    for (int i = t; i < GSIZE * 8; i += 512) dst[i] = acc[i];
}

template <int KCH>
__global__ __launch_bounds__(256) void k_epi1m(const float* __restrict__ g1part,
                                               const float* __restrict__ h1s,
                                               const float* __restrict__ dinv,
                                               const float* __restrict__ W2,  // 8x2
                                               const float* __restrict__ b1,
                                               float* __restrict__ xemb,
                                               float* __restrict__ h2s) {
    int i = blockIdx.x * blockDim.x + threadIdx.x;
    if (i >= NN) return;
    int g = i / GSIZE, il = i - g * GSIZE;
    float s[8];
#pragma unroll
    for (int m = 0; m < 8; ++m) s[m] = 0.0f;
#pragma unroll
    for (int j = 0; j < KCH; ++j) {
        const float4* p = (const float4*)(g1part + (((size_t)g * KCH + j) * GSIZE + il) * 8);
        float4 a = p[0], b = p[1];
        s[0] += a.x; s[1] += a.y; s[2] += a.z; s[3] += a.w;
        s[4] += b.x; s[5] += b.y; s[6] += b.z; s[7] += b.w;
    }
    float di = dinv[i];
    const float4* hp = (const float4*)(h1s + (size_t)i * 8);  // h1s = di * h1_raw
    float4 ha = hp[0], hb = hp[1];
    float hv[8] = {ha.x, ha.y, ha.z, ha.w, hb.x, hb.y, hb.z, hb.w};
    float e[8];
    // e = di*sum + di^2*h1_raw + b1 = di*(sum + h1s) + b1   (exact rewrite)
#pragma unroll
    for (int m = 0; m < 8; ++m) e[m] = di * (s[m] + hv[m]) + b1[m];
    float4* xo = reinterpret_cast<float4*>(xemb + (size_t)i * 8);
    xo[0] = make_float4(e[0], e[1], e[2], e[3]);
    xo[1] = make_float4(e[4], e[5], e[6], e[7]);
    float s0 = 0.0f, s1 = 0.0f;
#pragma unroll
    for (int m = 0; m < 8; ++m) {
        float rr = fmaxf(e[m], 0.0f);
        s0 += rr * W2[m * 2 + 0];
        s1 += rr * W2[m * 2 + 1];
    }
    // store dinv-prescaled layer-2 features
    *reinterpret_cast<float2*>(h2s + (size_t)i * 2) = make_float2(di * s0, di * s1);
}

__global__ __launch_bounds__(512) void k_gather2(const unsigned* __restrict__ cursors,
                                                 const unsigned long long* __restrict__ buckets,
                                                 int kch,
                                                 const float* __restrict__ h2s,
                                                 float* __restrict__ g2part) {
    __shared__ float acc[GSIZE * 2];  // 16000 B
    const int t = threadIdx.x;
    const int g = blockIdx.x / kch, j = blockIdx.x % kch;
    for (int i = t; i < GSIZE * 2; i += 512) acc[i] = 0.0f;
    __syncthreads();
    unsigned cu = cursors[g];
    const int cnt = (int)(cu < (unsigned)CAP ? cu : (unsigned)CAP);
    const int cpk = (cnt + kch - 1) / kch;
    const int lo = j * cpk;
    const int hi = (lo + cpk < cnt) ? lo + cpk : cnt;
    const unsigned long long* B = buckets + (size_t)g * CAP;
    for (int i = lo + t; i < hi; i += 512) {
        unsigned long long rec = B[i];
        unsigned pk = (unsigned)rec;
        int r = pk & 0x1FFFF;
        int cl = pk >> 17;
        float w = __uint_as_float((unsigned)(rec >> 32));
        float2 v = *(const float2*)(h2s + (size_t)r * 2);
        atomicAdd(&acc[cl * 2 + 0], w * v.x);
        atomicAdd(&acc[cl * 2 + 1], w * v.y);
    }
    __syncthreads();
    float* dst = g2part + ((size_t)g * kch + j) * (GSIZE * 2);
    for (int i = t; i < GSIZE * 2; i += 512) dst[i] = acc[i];
}

template <int KCH>
__global__ __launch_bounds__(256) void k_epi2m(const float* __restrict__ g2part,
                                               const float* __restrict__ h2s,
                                               const float* __restrict__ dinv,
                                               const float* __restrict__ b2,
                                               float* __restrict__ out) {
    int i = blockIdx.x * blockDim.x + threadIdx.x;
    if (i >= NN) return;
    int g = i / GSIZE, il = i - g * GSIZE;
    float s0 = 0.0f, s1 = 0.0f;
#pragma unroll
    for (int j = 0; j < KCH; ++j) {
        float2 p = *(const float2*)(g2part + (((size_t)g * KCH + j) * GSIZE + il) * 2);
        s0 += p.x; s1 += p.y;
    }
    float di = dinv[i];
    float2 h = *(const float2*)(h2s + (size_t)i * 2);  // h2s = di * h2_raw
    // out = di*sum + di^2*h2_raw + b2 = di*(sum + h2s) + b2
    *reinterpret_cast<float2*>(out + (size_t)i * 2) =
        make_float2(di * (s0 + h.x) + b2[0], di * (s1 + h.y) + b2[1]);
}

// ---------- FALLBACK (round-5, known-passing) ----------

__global__ __launch_bounds__(256) void k_prep(const void* __restrict__ ei,
                                              const float* __restrict__ ew,
                                              const int* __restrict__ flag,
                                              float* __restrict__ deg) {
    const int is64 = *flag;
    const int stride = gridDim.x * blockDim.x;
    const int nv = NE / 4;
    const float4* ewv = (const float4*)ew;
    for (int v = blockIdx.x * blockDim.x + threadIdx.x; v < nv; v += stride) {
        int c[4]; load4(ei, is64, v, NE, c);
        float4 w = ewv[v];
        atomAdd(&deg[c[0]], w.x);
        atomAdd(&deg[c[1]], w.y);
        atomAdd(&deg[c[2]], w.z);
        atomAdd(&deg[c[3]], w.w);
    }
}

__global__ __launch_bounds__(256) void k_node1(const float* __restrict__ x,
                                               const float* __restrict__ W1,
                                               const float* __restrict__ deg,
                                               float* __restrict__ dinv,
                                               float* __restrict__ h1) {
    __shared__ float sW[128];
    if (threadIdx.x < 128) sW[threadIdx.x] = W1[threadIdx.x];
    __syncthreads();
    int i = blockIdx.x * blockDim.x + threadIdx.x;
    if (i >= NN) return;
    float d = deg[i] + 1.0f;
    dinv[i] = rsqrtf(d);
    const float4* xp = reinterpret_cast<const float4*>(x + (size_t)i * 16);
    float acc[8];
#pragma unroll
    for (int j = 0; j < 8; ++j) acc[j] = 0.0f;
#pragma unroll
    for (int kq = 0; kq < 4; ++kq) {
        float4 v = xp[kq];
        float vv[4] = {v.x, v.y, v.z, v.w};
#pragma unroll
        for (int kk = 0; kk < 4; ++kk) {
            int k = kq * 4 + kk;
#pragma unroll
            for (int j = 0; j < 8; ++j) acc[j] += vv[kk] * sW[k * 8 + j];
        }
    }
    float4* hp = reinterpret_cast<float4*>(h1 + (size_t)i * 8);
    hp[0] = make_float4(acc[0], acc[1], acc[2], acc[3]);
    hp[1] = make_float4(acc[4], acc[5], acc[6], acc[7]);
}

__device__ __forceinline__ void agg1_edge(int r, int c, float w,
                                          const float* __restrict__ dinv,
                                          const float* __restrict__ h1,
                                          float* __restrict__ agg1) {
    float nrm = dinv[r] * w * dinv[c];
    const float4* hp = reinterpret_cast<const float4*>(h1 + (size_t)r * 8);
    float4 a = hp[0];
    float4 b = hp[1];
    float* o = agg1 + (size_t)c * 8;
    atomAdd(o + 0, nrm * a.x);
    atomAdd(o + 1, nrm * a.y);
    atomAdd(o + 2, nrm * a.z);
    atomAdd(o + 3, nrm * a.w);
    atomAdd(o + 4, nrm * b.x);
    atomAdd(o + 5, nrm * b.y);
    atomAdd(o + 6, nrm * b.z);
    atomAdd(o + 7, nrm * b.w);
}

__global__ __launch_bounds__(256) void k_agg1(const void* __restrict__ ei,
                                              const float* __restrict__ ew,
                                              const int* __restrict__ flag,
                                              const float* __restrict__ dinv,
                                              const float* __restrict__ h1,
                                              float* __restrict__ agg1) {
    const int is64 = *flag;
    const int stride = gridDim.x * blockDim.x;
    const int nv = NE / 4;
    const float4* ewv = (const float4*)ew;
    for (int v = blockIdx.x * blockDim.x + threadIdx.x; v < nv; v += stride) {
        int r[4], c[4];
        load4(ei, is64, v, 0, r);
        load4(ei, is64, v, NE, c);
        float4 w = ewv[v];
        agg1_edge(r[0], c[0], w.x, dinv, h1, agg1);
        agg1_edge(r[1], c[1], w.y, dinv, h1, agg1);
        agg1_edge(r[2], c[2], w.z, dinv, h1, agg1);
        agg1_edge(r[3], c[3], w.w, dinv, h1, agg1);
    }
}

__global__ __launch_bounds__(256) void k_epi1(const float* __restrict__ agg1,
                                              const float* __restrict__ h1,
                                              const float* __restrict__ dinv,
                                              const float* __restrict__ W2,
                                              const float* __restrict__ b1,
                                              float* __restrict__ xemb,
                                              float* __restrict__ h2) {
    int i = blockIdx.x * blockDim.x + threadIdx.x;
    if (i >= NN) return;
    float di = dinv[i];
    float d2 = di * di;
    const float4* ap = reinterpret_cast<const float4*>(agg1 + (size_t)i * 8);
    const float4* hp = reinterpret_cast<const float4*>(h1 + (size_t)i * 8);
    float4 a0 = ap[0], a1 = ap[1];
    float4 g0 = hp[0], g1 = hp[1];
    float e[8];
    e[0] = a0.x + d2 * g0.x + b1[0];
    e[1] = a0.y + d2 * g0.y + b1[1];
    e[2] = a0.z + d2 * g0.z + b1[2];
    e[3] = a0.w + d2 * g0.w + b1[3];
    e[4] = a1.x + d2 * g1.x + b1[4];
    e[5] = a1.y + d2 * g1.y + b1[5];
    e[6] = a1.z + d2 * g1.z + b1[6];
    e[7] = a1.w + d2 * g1.w + b1[7];
    float4* xo = reinterpret_cast<float4*>(xemb + (size_t)i * 8);
    xo[0] = make_float4(e[0], e[1], e[2], e[3]);
    xo[1] = make_float4(e[4], e[5], e[6], e[7]);
    float s0 = 0.0f, s1 = 0.0f;
#pragma unroll
    for (int j = 0; j < 8; ++j) {
        float r = fmaxf(e[j], 0.0f);
        s0 += r * W2[j * 2 + 0];
        s1 += r * W2[j * 2 + 1];
    }
    *reinterpret_cast<float2*>(h2 + (size_t)i * 2) = make_float2(s0, s1);
}

__device__ __forceinline__ void agg2_edge(int r, int c, float w,
                                          const float* __restrict__ dinv,
                                          const float* __restrict__ h2,
                                          float* __restrict__ agg2) {
    float nrm = dinv[r] * w * dinv[c];
    float2 v = *reinterpret_cast<const float2*>(h2 + (size_t)r * 2);
    float* o = agg2 + (size_t)c * 2;
    atomAdd(o + 0, nrm * v.x);
    atomAdd(o + 1, nrm * v.y);
}

__global__ __launch_bounds__(256) void k_agg2(const void* __restrict__ ei,
                                              const float* __restrict__ ew,
                                              const int* __restrict__ flag,
                                              const float* __restrict__ dinv,
                                              const float* __restrict__ h2,
                                              float* __restrict__ agg2) {
    const int is64 = *flag;
    const int stride = gridDim.x * blockDim.x;
    const int nv = NE / 4;
    const float4* ewv = (const float4*)ew;
    for (int v = blockIdx.x * blockDim.x + threadIdx.x; v < nv; v += stride) {
        int r[4], c[4];
        load4(ei, is64, v, 0, r);
        load4(ei, is64, v, NE, c);
        float4 w = ewv[v];
        agg2_edge(r[0], c[0], w.x, dinv, h2, agg2);
        agg2_edge(r[1], c[1], w.y, dinv, h2, agg2);
        agg2_edge(r[2], c[2], w.z, dinv, h2, agg2);
        agg2_edge(r[3], c[3], w.w, dinv, h2, agg2);
    }
}

__global__ __launch_bounds__(256) void k_epi2(const float* __restrict__ agg2,
                                              const float* __restrict__ h2,
                                              const float* __restrict__ dinv,
                                              const float* __restrict__ b2,
                                              float* __restrict__ out) {
    int i = blockIdx.x * blockDim.x + threadIdx.x;
    if (i >= NN) return;
    float di = dinv[i];
    float d2 = di * di;
    float2 a = *reinterpret_cast<const float2*>(agg2 + (size_t)i * 2);
    float2 h = *reinterpret_cast<const float2*>(h2 + (size_t)i * 2);
    *reinterpret_cast<float2*>(out + (size_t)i * 2) =
        make_float2(a.x + d2 * h.x + b2[0], a.y + d2 * h.y + b2[1]);
}

// ---------- host ----------

extern "C" void kernel_launch(void* const* d_in, const int* in_sizes, int n_in,
                              void* d_out, int out_size, void* d_ws, size_t ws_size,
                              hipStream_t stream) {
    const float* x  = (const float*)d_in[0];
    const void*  ei = d_in[1];                 // int32 confirmed (round-5 FETCH); detect = insurance
    const float* ew = (const float*)d_in[2];
    const float* W1 = (const float*)d_in[3];
    const float* b1 = (const float*)d_in[4];
    const float* W2 = (const float*)d_in[5];
    const float* b2 = (const float*)d_in[6];

    float* out  = (float*)d_out;               // [NN*2] then [NN*8] x_emb
    float* xemb = out + (size_t)NN * 2;

    const int NB = (NN + 255) / 256;

    // fast-path ws layout for a given KCH (all offsets 16B-aligned by construction)
    size_t o_buckets, o_g1, o_g2, o_deg, o_h1, o_h2, o_dinv, o_cur, o_flag, need;
    auto plan = [&](int kc) {
        size_t p = 0;
        o_buckets = p; p += (size_t)GROUPS * CAP * 8;             // 56.0 MB
        o_g1   = p; p += (size_t)GROUPS * kc * GSIZE * 8 * 4;     // 19.2 / 32.0 MB
        o_g2   = p; p += (size_t)GROUPS * kc * GSIZE * 2 * 4;     //  4.8 /  8.0 MB
        o_deg  = p; p += (size_t)GROUPS * kc * GSIZE * 4;         //  2.4 /  4.0 MB
        o_h1   = p; p += (size_t)NN * 8 * 4;                      //  3.2 MB
        o_h2   = p; p += (size_t)NN * 2 * 4;                      //  0.8 MB
        o_dinv = p; p += (size_t)NN * 4;                          //  0.4 MB
        o_cur  = p; p += GROUPS * 4;
        o_flag = p; p += 16;
        need = p;
    };

    int kch = 0;
    plan(10); if (ws_size >= need) kch = 10;            // ~104.4 MB: 500 gather blocks ~ 2/CU
    if (!kch) { plan(6); if (ws_size >= need) kch = 6; }// ~86.8 MB: 300 gather blocks

    char* ws = (char*)d_ws;

    if (kch) {
        unsigned long long* buckets = (unsigned long long*)(ws + o_buckets);
        float* g1part  = (float*)(ws + o_g1);
        float* g2part  = (float*)(ws + o_g2);
        float* degpart = (float*)(ws + o_deg);
        float* h1s     = (float*)(ws + o_h1);
        float* h2s     = (float*)(ws + o_h2);
        float* dinv    = (float*)(ws + o_dinv);
        unsigned* cursors = (unsigned*)(ws + o_cur);
        int* flag      = (int*)(ws + o_flag);

        hipMemsetAsync(cursors, 0, GROUPS * 4, stream);  // only accumulator needing zeros

        k_detect <<<1, 1, 0, stream>>>((const int*)ei, flag);
        k_bucket <<<NBB, 256, 0, stream>>>(ei, ew, flag, cursors, buckets);
        k_deg    <<<GROUPS * kch, 512, 0, stream>>>(cursors, buckets, kch, degpart);
        if (kch == 10) k_node1m<10><<<NB, 256, 0, stream>>>(x, W1, degpart, dinv, h1s);
        else           k_node1m<6> <<<NB, 256, 0, stream>>>(x, W1, degpart, dinv, h1s);
        k_gather1<<<GROUPS * kch, 512, 0, stream>>>(cursors, buckets, kch, h1s, g1part);
        if (kch == 10) k_epi1m<10><<<NB, 256, 0, stream>>>(g1part, h1s, dinv, W2, b1, xemb, h2s);
        else           k_epi1m<6> <<<NB, 256, 0, stream>>>(g1part, h1s, dinv, W2, b1, xemb, h2s);
        k_gather2<<<GROUPS * kch, 512, 0, stream>>>(cursors, buckets, kch, h2s, g2part);
        if (kch == 10) k_epi2m<10><<<NB, 256, 0, stream>>>(g2part, h2s, dinv, b2, out);
        else           k_epi2m<6> <<<NB, 256, 0, stream>>>(g2part, h2s, dinv, b2, out);
    } else {
        // ---- FALLBACK: round-5 passing path (atomic scatter) ----
        float* deg  = (float*)d_ws;                // NN
        float* agg1 = deg + NN;                    // NN*8
        float* agg2 = agg1 + (size_t)NN * 8;       // NN*2
        float* dinv = agg2 + (size_t)NN * 2;       // NN
        float* h1   = dinv + NN;                   // NN*8
        float* h2   = h1 + (size_t)NN * 8;         // NN*2
        int*   flag = (int*)(h2 + (size_t)NN * 2); // 1

        hipMemsetAsync(deg, 0, (size_t)NN * (1 + 8 + 2) * sizeof(float), stream);

        const int EB = 2048;
        k_detect<<<1, 1, 0, stream>>>((const int*)ei, flag);
        k_prep <<<EB, 256, 0, stream>>>(ei, ew, flag, deg);
        k_node1<<<NB, 256, 0, stream>>>(x, W1, deg, dinv, h1);
        k_agg1 <<<EB, 256, 0, stream>>>(ei, ew, flag, dinv, h1, agg1);
        k_epi1 <<<NB, 256, 0, stream>>>(agg1, h1, dinv, W2, b1, xemb, h2);
        k_agg2 <<<EB, 256, 0, stream>>>(ei, ew, flag, dinv, h2, agg2);
        k_epi2 <<<NB, 256, 0, stream>>>(agg2, h2, dinv, b2, out);
    }
}